// Round 6
// baseline (156.847 us; speedup 1.0000x reference)
//
#include <hip/hip_runtime.h>

typedef __bf16 bf16x8 __attribute__((ext_vector_type(8)));
typedef float  f32x16 __attribute__((ext_vector_type(16)));

// fp32 -> bf16 bits, round-to-nearest-even
__device__ __forceinline__ unsigned short f2bf_bits(float f) {
    unsigned int u = __builtin_bit_cast(unsigned int, f);
    u += 0x7FFFu + ((u >> 16) & 1u);
    return (unsigned short)(u >> 16);
}

// One workgroup = one channel c, 4 images (1 per wave). grid = 192*8 = 1536.
// 2 blocks/CU (reg-bound) -> 3 even rounds. Per row i the wave pipeline is:
//   [P: ds_read frags for row i+1] | mfma(row i) | [W: ds_write row i+2] [G: load row i+3]
// sched_barrier(0) fences pin this order so the compiler cannot roll the pipeline back.
// At each mfma exactly 14 newer ds ops are outstanding -> counted s_waitcnt lgkmcnt(14).
__global__ void __launch_bounds__(256, 2) dw5_51_kernel(
    const float* __restrict__ x,
    const float* __restrict__ w5,
    const float* __restrict__ w51,
    float* __restrict__ out)
{
    // weights, granule-major: g=kw/8 (8) x 128 rows x 8 elems
    __shared__ unsigned short wlds[8 * 1024];          // 16384 B
    // row buffers: 4 waves x 2 phases x (8 shift-copies x 136 elems)
    __shared__ unsigned short rowbuf[4][2][1088];      // 17408 B (total 33792 B)

    const int tid = threadIdx.x;
    const int wg  = blockIdx.x;
    const int c   = wg >> 3;      // 0..191
    const int bg  = wg & 7;       // 0..7

    // ---- stage effective weights, reversed rows, granule-major ----
    {
        const int s    = tid >> 1;          // 0..127
        const int half = tid & 1;
        const int kh   = 88 - s;
        const bool rowok = (kh >= 0) && (kh <= 50);
        #pragma unroll
        for (int j = 0; j < 32; ++j) {
            const int kw = half * 32 + j;
            float v = 0.0f;
            if (rowok && kw <= 50) {
                v = w51[c * 2601 + kh * 51 + kw];
                if (kh >= 23 && kh < 28 && kw >= 23 && kw < 28)
                    v += w5[c * 25 + (kh - 23) * 5 + (kw - 23)];
            }
            wlds[(kw >> 3) * 1024 + s * 8 + (kw & 7)] = f2bf_bits(v);
        }
    }

    const int lane = tid & 63;
    const int wv   = tid >> 6;        // wave 0..3
    const int b    = bg * 4 + wv;     // batch 0..31
    const int n32  = lane & 31;
    const int gg   = lane >> 5;
    const int q    = lane & 7;
    const int u8   = n32 >> 3;

    // zero this wave's row buffers (pad must stay 0; data slots rewritten every row)
    {
        unsigned int* z = (unsigned int*)&rowbuf[wv][0][0];
        #pragma unroll
        for (int i = 0; i < 17; ++i) z[lane + 64 * i] = 0u;
    }
    __syncthreads();

    const long imgbase = ((long)b * 192 + c) * 4096;
    const float* xrow = x + imgbase + lane;
    float* outp = out + imgbase;

    const int bidx  = 136 * q + 8 * u8 + 8 * gg;  // B-read base (elems); +16*t, t=0..5
    const int wbase = lane + 25;                  // write elem = wbase + 135*qq
    const int abase = gg * 1024 + n32 * 8;        // + srow*8 + ks*2048

    unsigned short* buf0 = &rowbuf[wv][0][0];
    unsigned short* buf1 = &rowbuf[wv][1][0];

    f32x16 acc00 = {}, acc01 = {}, acc10 = {}, acc11 = {};

    auto loadA = [&](bf16x8 (&A)[8], int r) {
        const int s0 = (63 - r) * 8 + abase;      // m-tile 0 rows
        const int s1 = (95 - r) * 8 + abase;      // m-tile 1 rows
        #pragma unroll
        for (int ks = 0; ks < 4; ++ks) {
            A[ks]     = *(const bf16x8*)&wlds[s0 + ks * 2048];
            A[4 + ks] = *(const bf16x8*)&wlds[s1 + ks * 2048];
        }
    };
    auto loadB = [&](bf16x8 (&D)[6], const unsigned short* p) {
        #pragma unroll
        for (int t = 0; t < 6; ++t) D[t] = *(const bf16x8*)&p[bidx + 16 * t];
    };
    auto domfma = [&](bf16x8 (&A)[8], bf16x8 (&D)[6], int r) {
        __builtin_amdgcn_sched_barrier(0);        // nothing moves into/out of the burst
        __builtin_amdgcn_s_setprio(1);
        if (r <= 56) {
            #pragma unroll
            for (int ks = 0; ks < 4; ++ks) {
                acc00 = __builtin_amdgcn_mfma_f32_32x32x16_bf16(A[ks], D[ks],     acc00, 0, 0, 0);
                acc01 = __builtin_amdgcn_mfma_f32_32x32x16_bf16(A[ks], D[ks + 2], acc01, 0, 0, 0);
            }
        }
        if (r >= 7) {
            #pragma unroll
            for (int ks = 0; ks < 4; ++ks) {
                acc10 = __builtin_amdgcn_mfma_f32_32x32x16_bf16(A[4 + ks], D[ks],     acc10, 0, 0, 0);
                acc11 = __builtin_amdgcn_mfma_f32_32x32x16_bf16(A[4 + ks], D[ks + 2], acc11, 0, 0, 0);
            }
        }
        __builtin_amdgcn_s_setprio(0);
        __builtin_amdgcn_sched_barrier(0);
    };
    auto writerow = [&](unsigned short* p, float v) {
        const unsigned short w0 = f2bf_bits(v);
        #pragma unroll
        for (int qq = 0; qq < 8; ++qq) p[wbase + 135 * qq] = w0;
    };

    // ---- prologue: rows 0,1 -> LDS; F(0) -> registers; xv = row 2 ----
    float xv = xrow[0];
    writerow(buf0, xv);
    xv = xrow[64];
    writerow(buf1, xv);
    xv = xrow[128];

    bf16x8 AE[8], AO[8], DE[6], DO[6];
    loadA(AE, 0);
    loadB(DE, buf0);

    // ---- main loop: rows 0..59 in static even/odd pairs ----
    #pragma unroll 1
    for (int i = 0; i < 60; i += 2) {
        // even sub-iter (row i)
        loadA(AO, i + 1);
        loadB(DO, buf1);                 // row i+1
        domfma(AE, DE, i);               // waits exactly the 14 P-reads above last iter's
        writerow(buf0, xv);              // row i+2 -> buf0 (before next P reads it)
        xv = xrow[(i + 3) * 64];         // row i+3
        // odd sub-iter (row i+1)
        loadA(AE, i + 2);
        loadB(DE, buf0);                 // row i+2 (FIFO after the write above)
        domfma(AO, DO, i + 1);
        writerow(buf1, xv);              // row i+3 -> buf1
        xv = xrow[(i + 4) * 64];         // row i+4 (i<=58 -> row<=62, in range)
    }

    // ---- epilogue: rows 60..63 ----
    loadA(AO, 61); loadB(DO, buf1);
    domfma(AE, DE, 60);
    writerow(buf0, xv);                  // row 62
    xv = xrow[63 * 64];                  // row 63

    loadA(AE, 62); loadB(DE, buf0);
    domfma(AO, DO, 61);
    writerow(buf1, xv);                  // row 63

    loadA(AO, 63); loadB(DO, buf1);
    domfma(AE, DE, 62);

    domfma(AO, DO, 63);

    // ---- epilogue: D layout (32x32): col = lane&31, row = (v&3) + 8*(v>>2) + 4*(lane>>5) ----
    #pragma unroll
    for (int v = 0; v < 16; ++v) {
        const int ho = (v & 3) + 8 * (v >> 2) + 4 * gg;
        outp[ho * 64 + n32]             = acc00[v];
        outp[ho * 64 + n32 + 32]        = acc01[v];
        outp[(ho + 32) * 64 + n32]      = acc10[v];
        outp[(ho + 32) * 64 + n32 + 32] = acc11[v];
    }
}

extern "C" void kernel_launch(void* const* d_in, const int* in_sizes, int n_in,
                              void* d_out, int out_size, void* d_ws, size_t ws_size,
                              hipStream_t stream) {
    (void)in_sizes; (void)n_in; (void)d_ws; (void)ws_size; (void)out_size;
    const float* x   = (const float*)d_in[0];
    const float* w5  = (const float*)d_in[1];
    const float* w51 = (const float*)d_in[2];
    float* out = (float*)d_out;
    dim3 grid(192 * 8), block(256);
    hipLaunchKernelGGL(dw5_51_kernel, grid, block, 0, stream, x, w5, w51, out);
}